// Round 2
// baseline (12400.349 us; speedup 1.0000x reference)
//
#include <hip/hip_runtime.h>
#include <hip/hip_bf16.h>
#include <hip/hip_fp16.h>
#include <cstdint>
#include <cstddef>

// ---------------- constants ----------------
#define N_ATOM 16384
#define M_NBR  12
#define NCRY   128
#define NM     (N_ATOM*M_NBR) // 196608

// output offsets (floats)
#define O_ZDEC 0
#define O_MU   44236800
#define O_LV   44237056
#define O_Z    44237312
#define O_TIF  44237568

__device__ __forceinline__ float sigmoidf_(float x){ return 1.f/(1.f+__expf(-x)); }
__device__ __forceinline__ float softplusf_(float x){ return fmaxf(x,0.f) + log1pf(__expf(-fabsf(x))); }
__device__ __forceinline__ uint32_t rotl32_(uint32_t x, int r){ return (x<<r)|(x>>(32-r)); }

// ---------------- eps = jax.random.normal(key(42), (128,2)) ----------------
// Partitionable threefry (JAX >= 0.5 default): per-element counter (hi=0, lo=j),
// 32-bit result = out0 ^ out1.
__global__ void gen_eps_kernel(float* __restrict__ eps){
  int j = threadIdx.x; // 256
  const uint32_t k0 = 0u, k1 = 42u;
  const uint32_t ks2 = k0 ^ k1 ^ 0x1BD11BDAu;
  uint32_t x0 = 0u + k0;            // hi + ks[0]
  uint32_t x1 = (uint32_t)j + k1;   // lo + ks[1]
#define RND_(r) { x0 += x1; x1 = rotl32_(x1, r); x1 ^= x0; }
  RND_(13) RND_(15) RND_(26) RND_(6)  x0 += k1;  x1 += ks2 + 1u;
  RND_(17) RND_(29) RND_(16) RND_(24) x0 += ks2; x1 += k0 + 2u;
  RND_(13) RND_(15) RND_(26) RND_(6)  x0 += k0;  x1 += k1 + 3u;
  RND_(17) RND_(29) RND_(16) RND_(24) x0 += k1;  x1 += ks2 + 4u;
  RND_(13) RND_(15) RND_(26) RND_(6)  x0 += ks2; x1 += k0 + 5u;
#undef RND_
  uint32_t bits = x0 ^ x1;
  float f = __uint_as_float((bits >> 9) | 0x3f800000u) - 1.0f; // [0,1)
  float u = __fadd_rn(__fmul_rn(f, 1.99999994f), -0.99999994f);
  u = fmaxf(-0.99999994f, u);
  // XLA/Giles erfinv f32
  float w = -log1pf(-u*u);
  float p;
  if (w < 5.0f){
    w -= 2.5f;
    p = 2.81022636e-08f;
    p = fmaf(p, w, 3.43273939e-07f);
    p = fmaf(p, w, -3.5233877e-06f);
    p = fmaf(p, w, -4.39150654e-06f);
    p = fmaf(p, w, 0.00021858087f);
    p = fmaf(p, w, -0.00125372503f);
    p = fmaf(p, w, -0.00417768164f);
    p = fmaf(p, w, 0.246640727f);
    p = fmaf(p, w, 1.50140941f);
  } else {
    w = sqrtf(w) - 3.0f;
    p = -0.000200214257f;
    p = fmaf(p, w, 0.000100950558f);
    p = fmaf(p, w, 0.00134934322f);
    p = fmaf(p, w, -0.00367342844f);
    p = fmaf(p, w, 0.00573950773f);
    p = fmaf(p, w, -0.0076224613f);
    p = fmaf(p, w, 0.00943887047f);
    p = fmaf(p, w, 1.00167406f);
    p = fmaf(p, w, 2.83297682f);
  }
  eps[j] = 1.41421356237f * (p * u);
}

// ---------------- total_input_fea output ----------------
__global__ void tif_kernel(const float* __restrict__ atom, const float* __restrict__ nbr,
                           const int* __restrict__ idx, float* __restrict__ out){
  int r = blockIdx.x; int c = threadIdx.x;
  if (c >= 225) return;
  int i = r / 12;
  float v;
  if (c < 92)       v = atom[i*92 + c];
  else if (c < 184) v = atom[idx[r]*92 + (c-92)];
  else              v = nbr[(size_t)r*41 + (c-184)];
  out[(size_t)r*225 + c] = v;
}

// ---------------- embeddings ----------------
__global__ void embed_atom_kernel(const float* __restrict__ atom, const float* __restrict__ W,
                                  const float* __restrict__ bias, float* __restrict__ a0){
  __shared__ float row[92];
  int i = blockIdx.x; int t = threadIdx.x; // 128
  if (t < 92) row[t] = atom[i*92+t];
  __syncthreads();
  float s = bias[t];
#pragma unroll
  for (int k=0;k<92;++k) s = fmaf(row[k], W[k*128+t], s);
  a0[(size_t)i*128+t] = s;
}

__global__ void embed_bond_kernel(const float* __restrict__ nbr, const float* __restrict__ W,
                                  const float* __restrict__ bias, float* __restrict__ nb0){
  __shared__ float rows[4][41];
  int r0 = blockIdx.x*4; int t = threadIdx.x; // 256
  if (t < 164) rows[t/41][t%41] = nbr[(size_t)r0*41 + t];
  __syncthreads();
  int rr = t >> 6, c = t & 63;
  float s = bias[c];
#pragma unroll
  for (int k=0;k<41;++k) s = fmaf(rows[rr][k], W[k*64+c], s);
  nb0[(size_t)(r0+rr)*64 + c] = s;
}

// ---------------- idx histogram ----------------
__global__ void cnt_kernel(const int* __restrict__ idx, int* __restrict__ cnt){
  int e = blockIdx.x*256 + threadIdx.x;
  if (e < NM) atomicAdd(&cnt[idx[e]], 1);
}

// ---------------- column sums for exact mean ----------------
// cs[0..127]   = sum_i a[i,c]          (self part; x12 applied later)
// cs[128..255] = sum_i cnt[i]*a[i,c]   (gathered part)
// cs[256..319] = sum_r nb[r,c]
__global__ void colsum_a_kernel(const float* __restrict__ a, const int* __restrict__ cnt,
                                double* __restrict__ cs){
  int c = threadIdx.x; // 128
  float p1 = 0.f, p2 = 0.f;
  int i0 = blockIdx.x*128;
  for (int i=i0; i<i0+128; ++i){
    float v = a[(size_t)i*128+c];
    p1 += v;
    p2 += (float)cnt[i] * v;
  }
  atomicAdd(&cs[c], (double)p1);
  atomicAdd(&cs[128+c], (double)p2);
}

__global__ void colsum_nb_kernel(const float* __restrict__ nb, double* __restrict__ cs){
  __shared__ float sh[4][64];
  int t = threadIdx.x; // 256
  int c = t & 63, pr = t >> 6;
  float p = 0.f;
  size_t r0 = (size_t)blockIdx.x * 512;
  for (size_t r = r0 + pr; r < r0 + 512; r += 4) p += nb[r*64 + c];
  sh[pr][c] = p;
  __syncthreads();
  if (pr == 0){
    float s = sh[0][c]+sh[1][c]+sh[2][c]+sh[3][c];
    atomicAdd(&cs[256+c], (double)s);
  }
}

// mean[o] = (sum_k colsumT[k]*W[k,o]) / NM   (exact: mean is linear in inputs)
__global__ void mean_kernel(const double* __restrict__ cs, const float* __restrict__ W,
                            int NO, float* __restrict__ mean){
  int o = blockIdx.x*64 + threadIdx.x;
  if (o >= NO) return;
  double s = 0.0;
  for (int k=0;k<128;++k)   s += 12.0*cs[k]*(double)W[(size_t)k*NO+o];
  for (int k=128;k<320;++k) s += cs[k]*(double)W[(size_t)k*NO+o];
  mean[o] = (float)(s / (double)NM);
}

// ---------------- conv GEMM: O[r,o] = sum_k total[r,k]*W[k,o] - mean[o] ----------------
// total[r] = [ a0[r/12] (128) | a0[idx[r]] (128) | nb0[r] (64) ], K = 320
// Stores mean-centered values as f16, accumulates per-column sum of squares (f64).
template<int NO>
__launch_bounds__(256)
__global__ void conv_gemm(const float* __restrict__ a0, const float* __restrict__ nb0,
                          const int* __restrict__ idx, const float* __restrict__ W,
                          const float* __restrict__ mean,
                          __half* __restrict__ O, double* __restrict__ ssq){
  __shared__ float As[32][68];
  __shared__ float Ws[32][68];
  __shared__ float red[16][68];
  const int row0 = blockIdx.x * 64;
  const int col0 = blockIdx.y * 64;
  const int t = threadIdx.x;
  const int tx = t & 15, ty = t >> 4;
  float acc[4][4] = {};
  for (int k0 = 0; k0 < 320; k0 += 32){
#pragma unroll
    for (int e = t; e < 2048; e += 256){
      int kk = e & 31, rr = e >> 5;
      int r = row0 + rr;
      int k = k0 + kk;
      float v;
      if (k < 128)      v = a0[(size_t)(r/12)*128 + k];
      else if (k < 256) v = a0[(size_t)idx[r]*128 + (k-128)];
      else              v = nb0[(size_t)r*64 + (k-256)];
      As[kk][rr] = v;
    }
#pragma unroll
    for (int e = t; e < 2048; e += 256){
      int cc = e & 63, kk = e >> 6;
      Ws[kk][cc] = W[(size_t)(k0+kk)*NO + col0 + cc];
    }
    __syncthreads();
#pragma unroll
    for (int kk = 0; kk < 32; ++kk){
      float4 a4 = *(const float4*)&As[kk][ty*4];
      float4 w4 = *(const float4*)&Ws[kk][tx*4];
      float a_[4] = {a4.x, a4.y, a4.z, a4.w};
      float w_[4] = {w4.x, w4.y, w4.z, w4.w};
#pragma unroll
      for (int p=0;p<4;++p)
#pragma unroll
        for (int q=0;q<4;++q) acc[p][q] = fmaf(a_[p], w_[q], acc[p][q]);
    }
    __syncthreads();
  }
  // epilogue: subtract exact mean, store f16, accumulate ssq
  float m4[4], sq[4] = {0.f,0.f,0.f,0.f};
#pragma unroll
  for (int q=0;q<4;++q) m4[q] = mean[col0 + tx*4 + q];
#pragma unroll
  for (int p=0;p<4;++p){
    int r = row0 + ty*4 + p;
    size_t base = (size_t)r*NO + col0 + tx*4;
#pragma unroll
    for (int q=0;q<4;++q){
      float xc = acc[p][q] - m4[q];
      O[base+q] = __float2half(xc);
      sq[q] += xc*xc;
    }
  }
#pragma unroll
  for (int q=0;q<4;++q) red[ty][tx*4+q] = sq[q];
  __syncthreads();
  if (t < 64){
    float s = 0.f;
#pragma unroll
    for (int g=0; g<16; ++g) s += red[g][t];
    atomicAdd(&ssq[col0 + t], (double)s);
  }
}

__global__ void finalize_rs(const double* __restrict__ ssq, int C, float* __restrict__ rs){
  int c = threadIdx.x;
  if (c < C) rs[c] = rsqrtf((float)(ssq[c] / (double)NM) + 1e-5f);
}

// ---------------- conv apply kernels (values are mean-centered: BN = x*rs*g + b) ----
__global__ void apply_ga(const __half* __restrict__ ga, const float* __restrict__ rs,
                         const float* __restrict__ g1a, const float* __restrict__ b1a,
                         float* __restrict__ asum){
  int i = blockIdx.x; int c = threadIdx.x; // 128
  float gf  = g1a[c]     * rs[c];      float bf_ = b1a[c];
  float gc  = g1a[c+128] * rs[c+128];  float bc_ = b1a[c+128];
  float s = 0.f;
  size_t base = (size_t)i*12*256;
#pragma unroll
  for (int j=0;j<12;++j){
    float vf = __half2float(ga[base + j*256 + c]);
    float vc = __half2float(ga[base + j*256 + c + 128]);
    s += sigmoidf_(fmaf(vf, gf, bf_)) * softplusf_(fmaf(vc, gc, bc_));
  }
  asum[(size_t)i*128+c] = s;
}

__global__ void asum_stats(const float* __restrict__ asum, double* __restrict__ st){
  int c = threadIdx.x; // 128
  float s1 = 0.f, s2 = 0.f;
  int i0 = blockIdx.x*128;
  for (int i=i0;i<i0+128;++i){
    float v = asum[(size_t)i*128+c];
    s1 += v; s2 += v*v;
  }
  atomicAdd(&st[c], (double)s1);
  atomicAdd(&st[128+c], (double)s2);
}

__global__ void finalize_mr2(const double* __restrict__ st, float* __restrict__ mr2){
  int c = threadIdx.x; // 128
  double mean = st[c] / (double)N_ATOM;
  double var  = st[128+c] / (double)N_ATOM - mean*mean;
  mr2[c]     = (float)mean;
  mr2[128+c] = rsqrtf((float)var + 1e-5f);
}

__global__ void apply_out1(const float* __restrict__ a0, const float* __restrict__ asum,
                           const float* __restrict__ mr2, const float* __restrict__ g2a,
                           const float* __restrict__ b2a, float* __restrict__ a1){
  int e = blockIdx.x*256 + threadIdx.x; // n*128
  int c = e & 127;
  float g = g2a[c]*mr2[128+c];
  float b = b2a[c] - mr2[c]*g;
  a1[e] = softplusf_(a0[e] + fmaf(asum[e], g, b));
}

__global__ void apply_gb(const __half* __restrict__ gb, const float* __restrict__ nb0,
                         const float* __restrict__ rs, const float* __restrict__ g1b,
                         const float* __restrict__ b1b, float* __restrict__ nb1){
  int e = blockIdx.x*256 + threadIdx.x; // NM*64
  int row = e >> 6, c = e & 63;
  float vf = __half2float(gb[(size_t)row*128 + c]);
  float vc = __half2float(gb[(size_t)row*128 + c + 64]);
  float gf  = g1b[c]    * rs[c];     float bf_ = b1b[c];
  float gc  = g1b[c+64] * rs[c+64];  float bc_ = b1b[c+64];
  nb1[e] = softplusf_(nb0[e] + sigmoidf_(fmaf(vf,gf,bf_)) * softplusf_(fmaf(vc,gc,bc_)));
}

// ---------------- pooling / VAE / decode ----------------
__global__ void pool_a_kernel(const float* __restrict__ a, float* __restrict__ pooled){
  int b = blockIdx.x; int c = threadIdx.x; // 128
  float s = 0.f;
  for (int i=0;i<128;++i) s += a[(size_t)((b<<7)+i)*128 + c];
  pooled[b*896 + c] = softplusf_(s * (1.f/128.f));
}

__launch_bounds__(768)
__global__ void pool_n_kernel(const float* __restrict__ nb, float* __restrict__ pooled){
  int b = blockIdx.x; int t = threadIdx.x; // 768
  float s = 0.f;
  for (int i=0;i<128;++i) s += nb[(size_t)((b<<7)+i)*768 + t];
  pooled[b*896 + 128 + t] = softplusf_(s * (1.f/128.f));
}

__global__ void muz_kernel(const float* __restrict__ pooled, const float* __restrict__ muW,
                           const float* __restrict__ mub, const float* __restrict__ lvW,
                           const float* __restrict__ lvb, const float* __restrict__ eps,
                           float* __restrict__ out_mu, float* __restrict__ out_lv,
                           float* __restrict__ out_z, float* __restrict__ zws){
  int t = threadIdx.x; // 256 -> (b,l)
  int b = t >> 1, l = t & 1;
  const float* pr = pooled + b*896;
  float smu = mub[l], slv = lvb[l];
  for (int k=0;k<896;++k){
    float p = pr[k];
    smu = fmaf(p, muW[k*2+l], smu);
    slv = fmaf(p, lvW[k*2+l], slv);
  }
  out_mu[t] = smu; out_lv[t] = slv;
  float zv = fmaf(eps[t], __expf(0.5f*slv), smu);
  out_z[t] = zv; zws[t] = zv;
}

__global__ void compute_f_kernel(const float* __restrict__ zws, const float* __restrict__ decW,
                                 const float* __restrict__ decb, const float* __restrict__ pooled,
                                 float* __restrict__ f){
  int b = blockIdx.x;
  float z0 = zws[b*2], z1 = zws[b*2+1];
  for (int k = threadIdx.x; k < 896; k += 256){
    float zd = fmaf(z0, decW[k], fmaf(z1, decW[896+k], decb[k]));
    f[b*896+k] = zd / pooled[b*896+k];
  }
}

__global__ void dec_atom_kernel(const float* __restrict__ a1, const float* __restrict__ f,
                                float* __restrict__ a2){
  int e = blockIdx.x*256+threadIdx.x; // n*128
  int c = e & 127; int b = e >> 14;
  a2[e] = softplusf_(a1[e] * f[b*896 + c]);
}

__global__ void dec_bond_kernel(const float* __restrict__ nb1, const float* __restrict__ f,
                                float* __restrict__ nb2){
  int i = blockIdx.x; int off = blockIdx.y*256 + threadIdx.x; // off < 768
  int b = i >> 7;
  size_t e = (size_t)i*768 + off;
  nb2[e] = softplusf_(nb1[e] * f[b*896 + 128 + off]);
}

// ---------------- final embeddings ----------------
__global__ void embed_atom2_kernel(const float* __restrict__ a, const float* __restrict__ W,
                                   const float* __restrict__ bias, float* __restrict__ za2){
  __shared__ float row[128];
  int i = blockIdx.x; int t = threadIdx.x; // 128
  row[t] = a[(size_t)i*128+t];
  __syncthreads();
  if (t < 92){
    float s = bias[t];
#pragma unroll
    for (int k=0;k<128;++k) s = fmaf(row[k], W[k*92+t], s);
    za2[(size_t)i*92+t] = sigmoidf_(s);
  }
}

__global__ void zdec_kernel(const float* __restrict__ za2, const float* __restrict__ nb,
                            const int* __restrict__ idx, const float* __restrict__ W,
                            const float* __restrict__ bias, float* __restrict__ out){
  __shared__ float vrow[64];
  int r = blockIdx.x; int t = threadIdx.x; // 256
  if (t < 64) vrow[t] = nb[(size_t)r*64 + t];
  __syncthreads();
  if (t >= 225) return;
  int i = r / 12;
  float v;
  if (t < 92)       v = za2[(size_t)i*92 + t];
  else if (t < 184) v = za2[(size_t)idx[r]*92 + (t-92)];
  else {
    int o = t - 184;
    float s = bias[o];
#pragma unroll
    for (int k=0;k<64;++k) s = fmaf(vrow[k], W[k*41+o], s);
    v = sigmoidf_(s);
  }
  out[(size_t)r*225 + t] = v;
}

// ---------------- host side ----------------
struct WsPlan {
  float *A, *NB, *asum, *pooled, *fbuf, *zws, *eps, *mean_a, *mean_b, *rs, *mr2;
  __half* big;
  int* cnt;
  double *cs, *ssq, *st;
};

static void conv_pass(const WsPlan& P, const int* idx,
                      const float* Wa, const float* Wb,
                      const float* g1a, const float* b1a, const float* g1b, const float* b1b,
                      const float* g2a, const float* b2a,
                      hipStream_t stream){
  // exact means (linear in inputs)
  hipMemsetAsync(P.cs, 0, 320*sizeof(double), stream);
  colsum_a_kernel<<<128, 128, 0, stream>>>(P.A, P.cnt, P.cs);
  colsum_nb_kernel<<<NM/512, 256, 0, stream>>>(P.NB, P.cs);
  mean_kernel<<<4, 64, 0, stream>>>(P.cs, Wa, 256, P.mean_a);
  mean_kernel<<<2, 64, 0, stream>>>(P.cs, Wb, 128, P.mean_b);
  // ga GEMM + stats
  hipMemsetAsync(P.ssq, 0, 256*sizeof(double), stream);
  dim3 ga_grid(NM/64, 4);
  conv_gemm<256><<<ga_grid, 256, 0, stream>>>(P.A, P.NB, idx, Wa, P.mean_a, P.big, P.ssq);
  finalize_rs<<<1, 256, 0, stream>>>(P.ssq, 256, P.rs);
  apply_ga<<<N_ATOM, 128, 0, stream>>>(P.big, P.rs, g1a, b1a, P.asum);
  // asum BN stats
  hipMemsetAsync(P.st, 0, 256*sizeof(double), stream);
  asum_stats<<<128, 128, 0, stream>>>(P.asum, P.st);
  finalize_mr2<<<1, 128, 0, stream>>>(P.st, P.mr2);
  // gb GEMM + stats (before in-place updates of A/NB)
  hipMemsetAsync(P.ssq, 0, 256*sizeof(double), stream);
  dim3 gb_grid(NM/64, 2);
  conv_gemm<128><<<gb_grid, 256, 0, stream>>>(P.A, P.NB, idx, Wb, P.mean_b, P.big, P.ssq);
  finalize_rs<<<1, 256, 0, stream>>>(P.ssq, 128, P.rs);
  // in-place updates
  apply_out1<<<N_ATOM*128/256, 256, 0, stream>>>(P.A, P.asum, P.mr2, g2a, b2a, P.A);
  apply_gb<<<NM*64/256, 256, 0, stream>>>(P.big, P.NB, P.rs, g1b, b1b, P.NB);
}

extern "C" void kernel_launch(void* const* d_in, const int* in_sizes, int n_in,
                              void* d_out, int out_size, void* d_ws, size_t ws_size,
                              hipStream_t stream) {
  (void)in_sizes; (void)n_in; (void)out_size; (void)ws_size;
  const float* atom_fea   = (const float*)d_in[0];
  const float* nbr_fea    = (const float*)d_in[1];
  const int*   idx        = (const int*)d_in[2];
  const float* emb_atom_W = (const float*)d_in[4];
  const float* emb_atom_b = (const float*)d_in[5];
  const float* emb_bond_W = (const float*)d_in[6];
  const float* emb_bond_b = (const float*)d_in[7];
  const float* emb_atom2_W= (const float*)d_in[8];
  const float* emb_atom2_b= (const float*)d_in[9];
  const float* emb_bond2_W= (const float*)d_in[10];
  const float* emb_bond2_b= (const float*)d_in[11];
  const float* mu_W       = (const float*)d_in[12];
  const float* mu_b       = (const float*)d_in[13];
  const float* lv_W       = (const float*)d_in[14];
  const float* lv_b       = (const float*)d_in[15];
  const float* dec_W      = (const float*)d_in[16];
  const float* dec_b      = (const float*)d_in[17];
  const float* c1_Wa  = (const float*)d_in[18];
  const float* c1_Wb  = (const float*)d_in[19];
  const float* c1_g1a = (const float*)d_in[20];
  const float* c1_b1a = (const float*)d_in[21];
  const float* c1_g1b = (const float*)d_in[22];
  const float* c1_b1b = (const float*)d_in[23];
  const float* c1_g2a = (const float*)d_in[24];
  const float* c1_b2a = (const float*)d_in[25];
  const float* c2_Wa  = (const float*)d_in[26];
  const float* c2_Wb  = (const float*)d_in[27];
  const float* c2_g1a = (const float*)d_in[28];
  const float* c2_b1a = (const float*)d_in[29];
  const float* c2_g1b = (const float*)d_in[30];
  const float* c2_b1b = (const float*)d_in[31];
  const float* c2_g2a = (const float*)d_in[32];
  const float* c2_b2a = (const float*)d_in[33];

  float* out = (float*)d_out;

  // ---------------- workspace layout ----------------
  WsPlan P;
  float* ws  = (float*)d_ws;
  P.A        = ws;                              // 2,097,152 f
  P.NB       = P.A + 2097152;                   // 12,582,912 f
  P.big      = (__half*)(P.NB + 12582912);      // 50,331,648 halves (100.7 MB)
  float* tail = (float*)((char*)P.big + (size_t)50331648*2);
  P.asum     = tail;                            // 2,097,152 f  (reused as za2)
  P.pooled   = P.asum + 2097152;                // 114,688
  P.fbuf     = P.pooled + 114688;               // 114,688
  P.zws      = P.fbuf + 114688;                 // 256
  P.eps      = P.zws + 256;                     // 256
  P.mean_a   = P.eps + 256;                     // 256
  P.mean_b   = P.mean_a + 256;                  // 128
  P.rs       = P.mean_b + 128;                  // 256
  P.mr2      = P.rs + 256;                      // 256
  P.cnt      = (int*)(P.mr2 + 256);             // 16384 int
  uintptr_t cs_addr = ((uintptr_t)(P.cnt + 16384) + 15) & ~(uintptr_t)15;
  P.cs       = (double*)cs_addr;                // 320 dbl
  P.ssq      = P.cs + 320;                      // 256 dbl
  P.st       = P.ssq + 256;                     // 256 dbl
  float* za2 = P.asum;

  gen_eps_kernel<<<1, 256, 0, stream>>>(P.eps);
  tif_kernel<<<NM, 256, 0, stream>>>(atom_fea, nbr_fea, idx, out + O_TIF);
  embed_atom_kernel<<<N_ATOM, 128, 0, stream>>>(atom_fea, emb_atom_W, emb_atom_b, P.A);
  embed_bond_kernel<<<NM/4, 256, 0, stream>>>(nbr_fea, emb_bond_W, emb_bond_b, P.NB);
  hipMemsetAsync(P.cnt, 0, N_ATOM*sizeof(int), stream);
  cnt_kernel<<<NM/256, 256, 0, stream>>>(idx, P.cnt);

  for (int L=0; L<3; ++L){
    conv_pass(P, idx, c1_Wa + (size_t)L*320*256, c1_Wb + (size_t)L*320*128,
              c1_g1a+L*256, c1_b1a+L*256, c1_g1b+L*128, c1_b1b+L*128,
              c1_g2a+L*128, c1_b2a+L*128, stream);
  }

  pool_a_kernel<<<NCRY, 128, 0, stream>>>(P.A, P.pooled);
  pool_n_kernel<<<NCRY, 768, 0, stream>>>(P.NB, P.pooled);
  muz_kernel<<<1, 256, 0, stream>>>(P.pooled, mu_W, mu_b, lv_W, lv_b, P.eps,
                                    out + O_MU, out + O_LV, out + O_Z, P.zws);
  compute_f_kernel<<<NCRY, 256, 0, stream>>>(P.zws, dec_W, dec_b, P.pooled, P.fbuf);
  dec_atom_kernel<<<N_ATOM*128/256, 256, 0, stream>>>(P.A, P.fbuf, P.A);
  dim3 gdb(N_ATOM, 3);
  dec_bond_kernel<<<gdb, 256, 0, stream>>>(P.NB, P.fbuf, P.NB);

  for (int L=0; L<3; ++L){
    conv_pass(P, idx, c2_Wa + (size_t)L*320*256, c2_Wb + (size_t)L*320*128,
              c2_g1a+L*256, c2_b1a+L*256, c2_g1b+L*128, c2_b1b+L*128,
              c2_g2a+L*128, c2_b2a+L*128, stream);
  }

  embed_atom2_kernel<<<N_ATOM, 128, 0, stream>>>(P.A, emb_atom2_W, emb_atom2_b, za2);
  zdec_kernel<<<NM, 256, 0, stream>>>(za2, P.NB, idx, emb_bond2_W, emb_bond2_b, out + O_ZDEC);
}

// Round 3
// 3523.626 us; speedup vs baseline: 3.5192x; 3.5192x over previous
//
#include <hip/hip_runtime.h>
#include <hip/hip_bf16.h>
#include <hip/hip_fp16.h>
#include <cstdint>
#include <cstddef>

// ---------------- constants ----------------
#define N_ATOM 16384
#define M_NBR  12
#define NCRY   128
#define NM     (N_ATOM*M_NBR) // 196608

// output offsets (floats)
#define O_ZDEC 0
#define O_MU   44236800
#define O_LV   44237056
#define O_Z    44237312
#define O_TIF  44237568

typedef unsigned short ushort_t;
typedef float f32x4 __attribute__((ext_vector_type(4)));
typedef int   i32x4 __attribute__((ext_vector_type(4)));

__device__ __forceinline__ float sigmoidf_(float x){ return 1.f/(1.f+__expf(-x)); }
__device__ __forceinline__ float softplusf_(float x){ return fmaxf(x,0.f) + log1pf(__expf(-fabsf(x))); }
__device__ __forceinline__ uint32_t rotl32_(uint32_t x, int r){ return (x<<r)|(x>>(32-r)); }
__device__ __forceinline__ float bf2f(ushort_t u){ return __uint_as_float(((uint32_t)u)<<16); }
__device__ __forceinline__ ushort_t f2bf(float x){
  uint32_t u = __float_as_uint(x);
  uint32_t r = (u + 0x7FFFu + ((u>>16)&1u)) >> 16;
  return (ushort_t)r;
}

__device__ __forceinline__ void mfma_bf16_16x16x32(f32x4& d, i32x4 a, i32x4 b){
  // D = A*B + C, C tied to D. A,B: 8 bf16 in 4 VGPRs each.
  asm("v_mfma_f32_16x16x32_bf16 %0, %1, %2, %0" : "+v"(d) : "v"(a), "v"(b));
}

// ---------------- eps = jax.random.normal(key(42), (128,2)) ----------------
__global__ void gen_eps_kernel(float* __restrict__ eps){
  int j = threadIdx.x; // 256
  const uint32_t k0 = 0u, k1 = 42u;
  const uint32_t ks2 = k0 ^ k1 ^ 0x1BD11BDAu;
  uint32_t x0 = 0u + k0;
  uint32_t x1 = (uint32_t)j + k1;
#define RND_(r) { x0 += x1; x1 = rotl32_(x1, r); x1 ^= x0; }
  RND_(13) RND_(15) RND_(26) RND_(6)  x0 += k1;  x1 += ks2 + 1u;
  RND_(17) RND_(29) RND_(16) RND_(24) x0 += ks2; x1 += k0 + 2u;
  RND_(13) RND_(15) RND_(26) RND_(6)  x0 += k0;  x1 += k1 + 3u;
  RND_(17) RND_(29) RND_(16) RND_(24) x0 += k1;  x1 += ks2 + 4u;
  RND_(13) RND_(15) RND_(26) RND_(6)  x0 += ks2; x1 += k0 + 5u;
#undef RND_
  uint32_t bits = x0 ^ x1;
  float f = __uint_as_float((bits >> 9) | 0x3f800000u) - 1.0f;
  float u = __fadd_rn(__fmul_rn(f, 1.99999994f), -0.99999994f);
  u = fmaxf(-0.99999994f, u);
  float w = -log1pf(-u*u);
  float p;
  if (w < 5.0f){
    w -= 2.5f;
    p = 2.81022636e-08f;
    p = fmaf(p, w, 3.43273939e-07f);
    p = fmaf(p, w, -3.5233877e-06f);
    p = fmaf(p, w, -4.39150654e-06f);
    p = fmaf(p, w, 0.00021858087f);
    p = fmaf(p, w, -0.00125372503f);
    p = fmaf(p, w, -0.00417768164f);
    p = fmaf(p, w, 0.246640727f);
    p = fmaf(p, w, 1.50140941f);
  } else {
    w = sqrtf(w) - 3.0f;
    p = -0.000200214257f;
    p = fmaf(p, w, 0.000100950558f);
    p = fmaf(p, w, 0.00134934322f);
    p = fmaf(p, w, -0.00367342844f);
    p = fmaf(p, w, 0.00573950773f);
    p = fmaf(p, w, -0.0076224613f);
    p = fmaf(p, w, 0.00943887047f);
    p = fmaf(p, w, 1.00167406f);
    p = fmaf(p, w, 2.83297682f);
  }
  eps[j] = 1.41421356237f * (p * u);
}

// ---------------- total_input_fea output ----------------
__global__ void tif_kernel(const float* __restrict__ atom, const float* __restrict__ nbr,
                           const int* __restrict__ idx, float* __restrict__ out){
  int r = blockIdx.x; int c = threadIdx.x;
  if (c >= 225) return;
  int i = r / 12;
  float v;
  if (c < 92)       v = atom[i*92 + c];
  else if (c < 184) v = atom[idx[r]*92 + (c-92)];
  else              v = nbr[(size_t)r*41 + (c-184)];
  out[(size_t)r*225 + c] = v;
}

// ---------------- embeddings (write bf16 masters) ----------------
__global__ void embed_atom_kernel(const float* __restrict__ atom, const float* __restrict__ W,
                                  const float* __restrict__ bias, ushort_t* __restrict__ a0){
  __shared__ float row[92];
  int i = blockIdx.x; int t = threadIdx.x; // 128
  if (t < 92) row[t] = atom[i*92+t];
  __syncthreads();
  float s = bias[t];
#pragma unroll
  for (int k=0;k<92;++k) s = fmaf(row[k], W[k*128+t], s);
  a0[(size_t)i*128+t] = f2bf(s);
}

__global__ void embed_bond_kernel(const float* __restrict__ nbr, const float* __restrict__ W,
                                  const float* __restrict__ bias, ushort_t* __restrict__ nb0){
  __shared__ float rows[4][41];
  int r0 = blockIdx.x*4; int t = threadIdx.x; // 256
  if (t < 164) rows[t/41][t%41] = nbr[(size_t)r0*41 + t];
  __syncthreads();
  int rr = t >> 6, c = t & 63;
  float s = bias[c];
#pragma unroll
  for (int k=0;k<41;++k) s = fmaf(rows[rr][k], W[k*64+c], s);
  nb0[(size_t)(r0+rr)*64 + c] = f2bf(s);
}

// ---------------- idx histogram ----------------
__global__ void cnt_kernel(const int* __restrict__ idx, int* __restrict__ cnt){
  int e = blockIdx.x*256 + threadIdx.x;
  if (e < NM) atomicAdd(&cnt[idx[e]], 1);
}

// ---------------- weight transpose + bf16: Wt[o][k] = bf16(W[k][o]) ----------------
__global__ void wtr_kernel(const float* __restrict__ W, int NO, ushort_t* __restrict__ Wt){
  __shared__ ushort_t tile[32][33];
  int k0 = blockIdx.x*32, o0 = blockIdx.y*32;
  int tx = threadIdx.x & 31, ty = threadIdx.x >> 5; // 256 thr
#pragma unroll
  for (int i = ty; i < 32; i += 8)
    tile[i][tx] = f2bf(W[(size_t)(k0+i)*NO + o0 + tx]);
  __syncthreads();
#pragma unroll
  for (int i = ty; i < 32; i += 8)
    Wt[(size_t)(o0+i)*320 + k0 + tx] = tile[tx][i];
}

// ---------------- column sums for exact mean (over bf16 masters) ----------------
__global__ void colsum_a_kernel(const ushort_t* __restrict__ a, const int* __restrict__ cnt,
                                double* __restrict__ cs){
  int c = threadIdx.x; // 128
  float p1 = 0.f, p2 = 0.f;
  int i0 = blockIdx.x*128;
  for (int i=i0; i<i0+128; ++i){
    float v = bf2f(a[(size_t)i*128+c]);
    p1 += v;
    p2 += (float)cnt[i] * v;
  }
  atomicAdd(&cs[c], (double)p1);
  atomicAdd(&cs[128+c], (double)p2);
}

__global__ void colsum_nb_kernel(const ushort_t* __restrict__ nb, double* __restrict__ cs){
  __shared__ float sh[4][64];
  int t = threadIdx.x; // 256
  int c = t & 63, pr = t >> 6;
  float p = 0.f;
  size_t r0 = (size_t)blockIdx.x * 512;
  for (size_t r = r0 + pr; r < r0 + 512; r += 4) p += bf2f(nb[r*64 + c]);
  sh[pr][c] = p;
  __syncthreads();
  if (pr == 0){
    float s = sh[0][c]+sh[1][c]+sh[2][c]+sh[3][c];
    atomicAdd(&cs[256+c], (double)s);
  }
}

__global__ void mean_kernel(const double* __restrict__ cs, const ushort_t* __restrict__ Wt,
                            int NO, float* __restrict__ mean){
  int o = blockIdx.x*64 + threadIdx.x;
  if (o >= NO) return;
  const ushort_t* wr = Wt + (size_t)o*320;
  double s = 0.0;
  for (int k=0;k<128;++k)   s += 12.0*cs[k]*(double)bf2f(wr[k]);
  for (int k=128;k<320;++k) s += cs[k]*(double)bf2f(wr[k]);
  mean[o] = (float)(s / (double)NM);
}

// ---------------- MFMA conv GEMM ----------------
// O[r,o] = sum_k total[r,k]*W[k,o] - mean[o]; total[r] = [a[r/12] | a[idx[r]] | nb[r]], K=320
// Tile 128 rows x 64 cols, 4 waves. B-panel resident in LDS (k-contiguous), A double-buffered.
template<int NO>
__launch_bounds__(256, 2)
__global__ void conv_gemm_mfma(const ushort_t* __restrict__ a_bf, const ushort_t* __restrict__ nb_bf,
                               const int* __restrict__ idx, const ushort_t* __restrict__ Wt,
                               const float* __restrict__ mean, __half* __restrict__ O,
                               float* __restrict__ ssq){
  __shared__ ushort_t Bs[64*328];     // [col][k], row stride 328 (41x16B) -> conflict-free
  __shared__ ushort_t As[2][128*40];  // [row][k-step 32], row stride 40 (5x16B) -> conflict-free
  __shared__ int      idxs[128];
  __shared__ float    sqred[64];
  const int t = threadIdx.x;
  const int lane = t & 63, w = t >> 6;
  const int row0 = blockIdx.x * 128;
  const int col0 = blockIdx.y * 64;

  // ---- B panel load: 64 rows of Wt (320 bf16 each) = 2560 x16B chunks
  {
    const ushort_t* src = Wt + (size_t)col0*320;
#pragma unroll
    for (int i = 0; i < 10; ++i){
      int e = t + i*256;
      int c = e / 40, ch = e - c*40;
      uint4 v = *(const uint4*)(src + (size_t)c*320 + ch*8);
      *(uint4*)&Bs[c*328 + ch*8] = v;
    }
  }
  if (t < 128) idxs[t] = idx[row0 + t];
  if (t < 64)  sqred[t] = 0.f;

  // ---- A staging: thread t stages rows (t>>2, +64) chunk (t&3); 4 lanes/row contiguous 64B
  const int g = t & 3;
  const int rbase = t >> 2;
  uint4 pre[2];
  auto stage_load = [&](int ks){
#pragma unroll
    for (int h = 0; h < 2; ++h){
      int rr = rbase + h*64;
      int r  = row0 + rr;
      const ushort_t* p;
      if (ks < 4)       p = a_bf + (size_t)(r/12)*128 + ks*32 + g*8;
      else if (ks < 8)  p = a_bf + (size_t)idxs[rr]*128 + (ks-4)*32 + g*8;
      else              p = nb_bf + (size_t)r*64 + (ks-8)*32 + g*8;
      pre[h] = *(const uint4*)p;
    }
  };
  auto stage_write = [&](int b_){
#pragma unroll
    for (int h = 0; h < 2; ++h){
      int rr = rbase + h*64;
      *(uint4*)&As[b_][rr*40 + g*8] = pre[h];
    }
  };

  stage_load(0); stage_write(0);
  __syncthreads();

  f32x4 acc[2][4] = {};
#define ACCS_ "+v"(acc[0][0]),"+v"(acc[0][1]),"+v"(acc[0][2]),"+v"(acc[0][3]),"+v"(acc[1][0]),"+v"(acc[1][1]),"+v"(acc[1][2]),"+v"(acc[1][3])
  asm volatile("s_nop 3" : ACCS_);   // VALU zero-init -> MFMA SrcC hazard guard

  const int lm = lane & 15, lg = lane >> 4;
  int buf = 0;
#pragma unroll
  for (int ks = 0; ks < 10; ++ks){
    if (ks < 9) stage_load(ks+1);
    i32x4 bfr[4], afr[2];
#pragma unroll
    for (int fn = 0; fn < 4; ++fn)
      bfr[fn] = *(const i32x4*)&Bs[(fn*16 + lm)*328 + ks*32 + lg*8];
#pragma unroll
    for (int fm = 0; fm < 2; ++fm)
      afr[fm] = *(const i32x4*)&As[buf][(w*32 + fm*16 + lm)*40 + lg*8];
#pragma unroll
    for (int fm = 0; fm < 2; ++fm)
#pragma unroll
      for (int fn = 0; fn < 4; ++fn)
        mfma_bf16_16x16x32(acc[fm][fn], afr[fm], bfr[fn]);
    if (ks < 9) stage_write(buf^1);
    __syncthreads();
    buf ^= 1;
  }

  asm volatile("s_nop 7\n\ts_nop 7" : ACCS_);  // MFMA -> VALU read hazard guard
#undef ACCS_

  // epilogue: subtract exact mean, store f16, reduce ssq
  float m4[4];
#pragma unroll
  for (int fn=0; fn<4; ++fn) m4[fn] = mean[col0 + fn*16 + lm];
  float sq[4] = {0.f,0.f,0.f,0.f};
#pragma unroll
  for (int fm=0; fm<2; ++fm){
#pragma unroll
    for (int fn=0; fn<4; ++fn){
#pragma unroll
      for (int j=0; j<4; ++j){
        float xc = acc[fm][fn][j] - m4[fn];
        int r = row0 + w*32 + fm*16 + lg*4 + j;
        O[(size_t)r*NO + col0 + fn*16 + lm] = __float2half(xc);
        sq[fn] += xc*xc;
      }
    }
  }
#pragma unroll
  for (int fn=0; fn<4; ++fn) atomicAdd(&sqred[fn*16 + lm], sq[fn]);
  __syncthreads();
  if (t < 64) atomicAdd(&ssq[col0 + t], sqred[t]);
}

__global__ void finalize_rs(const float* __restrict__ ssq, int C, float* __restrict__ rs){
  int c = threadIdx.x;
  if (c < C) rs[c] = rsqrtf(ssq[c]/(float)NM + 1e-5f);
}

// ---------------- conv apply kernels (values mean-centered: BN = x*rs*g + b) ----
__global__ void apply_ga(const __half* __restrict__ ga, const float* __restrict__ rs,
                         const float* __restrict__ g1a, const float* __restrict__ b1a,
                         float* __restrict__ asum){
  int i = blockIdx.x; int c = threadIdx.x; // 128
  float gf  = g1a[c]     * rs[c];      float bf_ = b1a[c];
  float gc  = g1a[c+128] * rs[c+128];  float bc_ = b1a[c+128];
  float s = 0.f;
  size_t base = (size_t)i*12*256;
#pragma unroll
  for (int j=0;j<12;++j){
    float vf = __half2float(ga[base + j*256 + c]);
    float vc = __half2float(ga[base + j*256 + c + 128]);
    s += sigmoidf_(fmaf(vf, gf, bf_)) * softplusf_(fmaf(vc, gc, bc_));
  }
  asum[(size_t)i*128+c] = s;
}

__global__ void asum_stats(const float* __restrict__ asum, double* __restrict__ st){
  int c = threadIdx.x; // 128
  float s1 = 0.f, s2 = 0.f;
  int i0 = blockIdx.x*128;
  for (int i=i0;i<i0+128;++i){
    float v = asum[(size_t)i*128+c];
    s1 += v; s2 += v*v;
  }
  atomicAdd(&st[c], (double)s1);
  atomicAdd(&st[128+c], (double)s2);
}

__global__ void finalize_mr2(const double* __restrict__ st, float* __restrict__ mr2){
  int c = threadIdx.x; // 128
  double mean = st[c] / (double)N_ATOM;
  double var  = st[128+c] / (double)N_ATOM - mean*mean;
  mr2[c]     = (float)mean;
  mr2[128+c] = rsqrtf((float)var + 1e-5f);
}

__global__ void apply_out1(ushort_t* __restrict__ a0, const float* __restrict__ asum,
                           const float* __restrict__ mr2, const float* __restrict__ g2a,
                           const float* __restrict__ b2a){
  int e = blockIdx.x*256 + threadIdx.x; // n*128
  int c = e & 127;
  float g = g2a[c]*mr2[128+c];
  float b = b2a[c] - mr2[c]*g;
  a0[e] = f2bf(softplusf_(bf2f(a0[e]) + fmaf(asum[e], g, b)));
}

__global__ void apply_gb(const __half* __restrict__ gb, ushort_t* __restrict__ nb,
                         const float* __restrict__ rs, const float* __restrict__ g1b,
                         const float* __restrict__ b1b){
  int e = blockIdx.x*256 + threadIdx.x; // NM*64
  int row = e >> 6, c = e & 63;
  float vf = __half2float(gb[(size_t)row*128 + c]);
  float vc = __half2float(gb[(size_t)row*128 + c + 64]);
  float gf  = g1b[c]    * rs[c];     float bf_ = b1b[c];
  float gc  = g1b[c+64] * rs[c+64];  float bc_ = b1b[c+64];
  nb[e] = f2bf(softplusf_(bf2f(nb[e]) + sigmoidf_(fmaf(vf,gf,bf_)) * softplusf_(fmaf(vc,gc,bc_))));
}

// ---------------- pooling / VAE / decode ----------------
__global__ void pool_a_kernel(const ushort_t* __restrict__ a, float* __restrict__ pooled){
  int b = blockIdx.x; int c = threadIdx.x; // 128
  float s = 0.f;
  for (int i=0;i<128;++i) s += bf2f(a[(size_t)((b<<7)+i)*128 + c]);
  pooled[b*896 + c] = softplusf_(s * (1.f/128.f));
}

__launch_bounds__(768)
__global__ void pool_n_kernel(const ushort_t* __restrict__ nb, float* __restrict__ pooled){
  int b = blockIdx.x; int t = threadIdx.x; // 768
  float s = 0.f;
  for (int i=0;i<128;++i) s += bf2f(nb[(size_t)((b<<7)+i)*768 + t]);
  pooled[b*896 + 128 + t] = softplusf_(s * (1.f/128.f));
}

__global__ void muz_kernel(const float* __restrict__ pooled, const float* __restrict__ muW,
                           const float* __restrict__ mub, const float* __restrict__ lvW,
                           const float* __restrict__ lvb, const float* __restrict__ eps,
                           float* __restrict__ out_mu, float* __restrict__ out_lv,
                           float* __restrict__ out_z, float* __restrict__ zws){
  int t = threadIdx.x; // 256 -> (b,l)
  int b = t >> 1, l = t & 1;
  const float* pr = pooled + b*896;
  float smu = mub[l], slv = lvb[l];
  for (int k=0;k<896;++k){
    float p = pr[k];
    smu = fmaf(p, muW[k*2+l], smu);
    slv = fmaf(p, lvW[k*2+l], slv);
  }
  out_mu[t] = smu; out_lv[t] = slv;
  float zv = fmaf(eps[t], __expf(0.5f*slv), smu);
  out_z[t] = zv; zws[t] = zv;
}

__global__ void compute_f_kernel(const float* __restrict__ zws, const float* __restrict__ decW,
                                 const float* __restrict__ decb, const float* __restrict__ pooled,
                                 float* __restrict__ f){
  int b = blockIdx.x;
  float z0 = zws[b*2], z1 = zws[b*2+1];
  for (int k = threadIdx.x; k < 896; k += 256){
    float zd = fmaf(z0, decW[k], fmaf(z1, decW[896+k], decb[k]));
    f[b*896+k] = zd / pooled[b*896+k];
  }
}

__global__ void dec_atom_kernel(ushort_t* __restrict__ a, const float* __restrict__ f){
  int e = blockIdx.x*256+threadIdx.x; // n*128
  int c = e & 127; int b = e >> 14;
  a[e] = f2bf(softplusf_(bf2f(a[e]) * f[b*896 + c]));
}

__global__ void dec_bond_kernel(ushort_t* __restrict__ nb, const float* __restrict__ f){
  int i = blockIdx.x; int off = blockIdx.y*256 + threadIdx.x; // off < 768
  int b = i >> 7;
  size_t e = (size_t)i*768 + off;
  nb[e] = f2bf(softplusf_(bf2f(nb[e]) * f[b*896 + 128 + off]));
}

// ---------------- final embeddings ----------------
__global__ void embed_atom2_kernel(const ushort_t* __restrict__ a, const float* __restrict__ W,
                                   const float* __restrict__ bias, float* __restrict__ za2){
  __shared__ float row[128];
  int i = blockIdx.x; int t = threadIdx.x; // 128
  row[t] = bf2f(a[(size_t)i*128+t]);
  __syncthreads();
  if (t < 92){
    float s = bias[t];
#pragma unroll
    for (int k=0;k<128;++k) s = fmaf(row[k], W[k*92+t], s);
    za2[(size_t)i*92+t] = sigmoidf_(s);
  }
}

__global__ void zdec_kernel(const float* __restrict__ za2, const ushort_t* __restrict__ nb,
                            const int* __restrict__ idx, const float* __restrict__ W,
                            const float* __restrict__ bias, float* __restrict__ out){
  __shared__ float vrow[64];
  int r = blockIdx.x; int t = threadIdx.x; // 256
  if (t < 64) vrow[t] = bf2f(nb[(size_t)r*64 + t]);
  __syncthreads();
  if (t >= 225) return;
  int i = r / 12;
  float v;
  if (t < 92)       v = za2[(size_t)i*92 + t];
  else if (t < 184) v = za2[(size_t)idx[r]*92 + (t-92)];
  else {
    int o = t - 184;
    float s = bias[o];
#pragma unroll
    for (int k=0;k<64;++k) s = fmaf(vrow[k], W[k*41+o], s);
    v = sigmoidf_(s);
  }
  out[(size_t)r*225 + t] = v;
}

// ---------------- host side ----------------
struct WsPlan {
  ushort_t *Abf, *NBbf, *Wta, *Wtb;
  __half* big;
  float *asum, *pooled, *fbuf, *zws, *eps, *mean_a, *mean_b, *rs, *mr2, *ssq;
  int* cnt;
  double *cs, *st;
};

static void conv_pass(const WsPlan& P, const int* idx,
                      const float* Wa, const float* Wb,
                      const float* g1a, const float* b1a, const float* g1b, const float* b1b,
                      const float* g2a, const float* b2a,
                      hipStream_t stream){
  wtr_kernel<<<dim3(10,8), 256, 0, stream>>>(Wa, 256, P.Wta);
  wtr_kernel<<<dim3(10,4), 256, 0, stream>>>(Wb, 128, P.Wtb);
  // exact means over bf16 inputs
  hipMemsetAsync(P.cs, 0, 320*sizeof(double), stream);
  colsum_a_kernel<<<128, 128, 0, stream>>>(P.Abf, P.cnt, P.cs);
  colsum_nb_kernel<<<NM/512, 256, 0, stream>>>(P.NBbf, P.cs);
  mean_kernel<<<4, 64, 0, stream>>>(P.cs, P.Wta, 256, P.mean_a);
  mean_kernel<<<2, 64, 0, stream>>>(P.cs, P.Wtb, 128, P.mean_b);
  // ga GEMM + stats
  hipMemsetAsync(P.ssq, 0, 256*sizeof(float), stream);
  conv_gemm_mfma<256><<<dim3(1536,4), 256, 0, stream>>>(P.Abf, P.NBbf, idx, P.Wta, P.mean_a, P.big, P.ssq);
  finalize_rs<<<1, 256, 0, stream>>>(P.ssq, 256, P.rs);
  apply_ga<<<N_ATOM, 128, 0, stream>>>(P.big, P.rs, g1a, b1a, P.asum);
  // asum BN stats
  hipMemsetAsync(P.st, 0, 256*sizeof(double), stream);
  asum_stats<<<128, 128, 0, stream>>>(P.asum, P.st);
  finalize_mr2<<<1, 128, 0, stream>>>(P.st, P.mr2);
  // gb GEMM + stats (before in-place updates of Abf/NBbf)
  hipMemsetAsync(P.ssq, 0, 256*sizeof(float), stream);
  conv_gemm_mfma<128><<<dim3(1536,2), 256, 0, stream>>>(P.Abf, P.NBbf, idx, P.Wtb, P.mean_b, P.big, P.ssq);
  finalize_rs<<<1, 256, 0, stream>>>(P.ssq, 128, P.rs);
  // in-place activations
  apply_out1<<<N_ATOM*128/256, 256, 0, stream>>>(P.Abf, P.asum, P.mr2, g2a, b2a);
  apply_gb<<<NM*64/256, 256, 0, stream>>>(P.big, P.NBbf, P.rs, g1b, b1b);
}

extern "C" void kernel_launch(void* const* d_in, const int* in_sizes, int n_in,
                              void* d_out, int out_size, void* d_ws, size_t ws_size,
                              hipStream_t stream) {
  (void)in_sizes; (void)n_in; (void)out_size; (void)ws_size;
  const float* atom_fea   = (const float*)d_in[0];
  const float* nbr_fea    = (const float*)d_in[1];
  const int*   idx        = (const int*)d_in[2];
  const float* emb_atom_W = (const float*)d_in[4];
  const float* emb_atom_b = (const float*)d_in[5];
  const float* emb_bond_W = (const float*)d_in[6];
  const float* emb_bond_b = (const float*)d_in[7];
  const float* emb_atom2_W= (const float*)d_in[8];
  const float* emb_atom2_b= (const float*)d_in[9];
  const float* emb_bond2_W= (const float*)d_in[10];
  const float* emb_bond2_b= (const float*)d_in[11];
  const float* mu_W       = (const float*)d_in[12];
  const float* mu_b       = (const float*)d_in[13];
  const float* lv_W       = (const float*)d_in[14];
  const float* lv_b       = (const float*)d_in[15];
  const float* dec_W      = (const float*)d_in[16];
  const float* dec_b      = (const float*)d_in[17];
  const float* c1_Wa  = (const float*)d_in[18];
  const float* c1_Wb  = (const float*)d_in[19];
  const float* c1_g1a = (const float*)d_in[20];
  const float* c1_b1a = (const float*)d_in[21];
  const float* c1_g1b = (const float*)d_in[22];
  const float* c1_b1b = (const float*)d_in[23];
  const float* c1_g2a = (const float*)d_in[24];
  const float* c1_b2a = (const float*)d_in[25];
  const float* c2_Wa  = (const float*)d_in[26];
  const float* c2_Wb  = (const float*)d_in[27];
  const float* c2_g1a = (const float*)d_in[28];
  const float* c2_b1a = (const float*)d_in[29];
  const float* c2_g1b = (const float*)d_in[30];
  const float* c2_b1b = (const float*)d_in[31];
  const float* c2_g2a = (const float*)d_in[32];
  const float* c2_b2a = (const float*)d_in[33];

  float* out = (float*)d_out;

  // ---------------- workspace layout ----------------
  WsPlan P;
  char* w = (char*)d_ws;
  auto alloc = [&](size_t bytes) -> char* {
    char* p = w; w += (bytes + 255) & ~(size_t)255; return p;
  };
  P.Abf    = (ushort_t*)alloc((size_t)N_ATOM*128*2);     // 4 MB
  P.NBbf   = (ushort_t*)alloc((size_t)NM*64*2);          // 24 MB
  P.big    = (__half*)  alloc((size_t)NM*256*2);         // 96 MB
  P.asum   = (float*)   alloc((size_t)N_ATOM*128*4);     // 8 MB
  P.pooled = (float*)   alloc(114688*4);
  P.fbuf   = (float*)   alloc(114688*4);
  P.Wta    = (ushort_t*)alloc(256*320*2);
  P.Wtb    = (ushort_t*)alloc(128*320*2);
  P.zws    = (float*)   alloc(256*4);
  P.eps    = (float*)   alloc(256*4);
  P.mean_a = (float*)   alloc(256*4);
  P.mean_b = (float*)   alloc(128*4);
  P.rs     = (float*)   alloc(256*4);
  P.mr2    = (float*)   alloc(256*4);
  P.ssq    = (float*)   alloc(256*4);
  P.cnt    = (int*)     alloc(N_ATOM*4);
  P.cs     = (double*)  alloc(320*8);
  P.st     = (double*)  alloc(256*8);
  float* za2 = P.asum; // reuse (free after conv stacks)

  gen_eps_kernel<<<1, 256, 0, stream>>>(P.eps);
  tif_kernel<<<NM, 256, 0, stream>>>(atom_fea, nbr_fea, idx, out + O_TIF);
  embed_atom_kernel<<<N_ATOM, 128, 0, stream>>>(atom_fea, emb_atom_W, emb_atom_b, P.Abf);
  embed_bond_kernel<<<NM/4, 256, 0, stream>>>(nbr_fea, emb_bond_W, emb_bond_b, P.NBbf);
  hipMemsetAsync(P.cnt, 0, N_ATOM*sizeof(int), stream);
  cnt_kernel<<<NM/256, 256, 0, stream>>>(idx, P.cnt);

  for (int L=0; L<3; ++L){
    conv_pass(P, idx, c1_Wa + (size_t)L*320*256, c1_Wb + (size_t)L*320*128,
              c1_g1a+L*256, c1_b1a+L*256, c1_g1b+L*128, c1_b1b+L*128,
              c1_g2a+L*128, c1_b2a+L*128, stream);
  }

  pool_a_kernel<<<NCRY, 128, 0, stream>>>(P.Abf, P.pooled);
  pool_n_kernel<<<NCRY, 768, 0, stream>>>(P.NBbf, P.pooled);
  muz_kernel<<<1, 256, 0, stream>>>(P.pooled, mu_W, mu_b, lv_W, lv_b, P.eps,
                                    out + O_MU, out + O_LV, out + O_Z, P.zws);
  compute_f_kernel<<<NCRY, 256, 0, stream>>>(P.zws, dec_W, dec_b, P.pooled, P.fbuf);
  dec_atom_kernel<<<N_ATOM*128/256, 256, 0, stream>>>(P.Abf, P.fbuf);
  dim3 gdb(N_ATOM, 3);
  dec_bond_kernel<<<gdb, 256, 0, stream>>>(P.NBbf, P.fbuf);

  for (int L=0; L<3; ++L){
    conv_pass(P, idx, c2_Wa + (size_t)L*320*256, c2_Wb + (size_t)L*320*128,
              c2_g1a+L*256, c2_b1a+L*256, c2_g1b+L*128, c2_b1b+L*128,
              c2_g2a+L*128, c2_b2a+L*128, stream);
  }

  embed_atom2_kernel<<<N_ATOM, 128, 0, stream>>>(P.Abf, emb_atom2_W, emb_atom2_b, za2);
  zdec_kernel<<<NM, 256, 0, stream>>>(za2, P.NBbf, idx, emb_bond2_W, emb_bond2_b, out + O_ZDEC);
}

// Round 4
// 3136.792 us; speedup vs baseline: 3.9532x; 1.1233x over previous
//
#include <hip/hip_runtime.h>
#include <hip/hip_bf16.h>
#include <hip/hip_fp16.h>
#include <cstdint>
#include <cstddef>

// ---------------- constants ----------------
#define N_ATOM 16384
#define M_NBR  12
#define NCRY   128
#define NM     (N_ATOM*M_NBR) // 196608

// output offsets (floats)
#define O_ZDEC 0
#define O_MU   44236800
#define O_LV   44237056
#define O_Z    44237312
#define O_TIF  44237568

typedef unsigned short ushort_t;
typedef float f32x4 __attribute__((ext_vector_type(4)));
typedef int   i32x4 __attribute__((ext_vector_type(4)));

__device__ __forceinline__ float sigmoidf_(float x){ return 1.f/(1.f+__expf(-x)); }
__device__ __forceinline__ float softplusf_(float x){ return fmaxf(x,0.f) + log1pf(__expf(-fabsf(x))); }
__device__ __forceinline__ uint32_t rotl32_(uint32_t x, int r){ return (x<<r)|(x>>(32-r)); }
__device__ __forceinline__ float bf2f(ushort_t u){ return __uint_as_float(((uint32_t)u)<<16); }
__device__ __forceinline__ ushort_t f2bf(float x){
  uint32_t u = __float_as_uint(x);
  uint32_t r = (u + 0x7FFFu + ((u>>16)&1u)) >> 16;
  return (ushort_t)r;
}

__device__ __forceinline__ void mfma_bf16_16x16x32(f32x4& d, i32x4 a, i32x4 b){
  asm("v_mfma_f32_16x16x32_bf16 %0, %1, %2, %0" : "+v"(d) : "v"(a), "v"(b));
}

// ---------------- eps = jax.random.normal(key(42), (128,2)) ----------------
__global__ void gen_eps_kernel(float* __restrict__ eps){
  int j = threadIdx.x; // 256
  const uint32_t k0 = 0u, k1 = 42u;
  const uint32_t ks2 = k0 ^ k1 ^ 0x1BD11BDAu;
  uint32_t x0 = 0u + k0;
  uint32_t x1 = (uint32_t)j + k1;
#define RND_(r) { x0 += x1; x1 = rotl32_(x1, r); x1 ^= x0; }
  RND_(13) RND_(15) RND_(26) RND_(6)  x0 += k1;  x1 += ks2 + 1u;
  RND_(17) RND_(29) RND_(16) RND_(24) x0 += ks2; x1 += k0 + 2u;
  RND_(13) RND_(15) RND_(26) RND_(6)  x0 += k0;  x1 += k1 + 3u;
  RND_(17) RND_(29) RND_(16) RND_(24) x0 += k1;  x1 += ks2 + 4u;
  RND_(13) RND_(15) RND_(26) RND_(6)  x0 += ks2; x1 += k0 + 5u;
#undef RND_
  uint32_t bits = x0 ^ x1;
  float f = __uint_as_float((bits >> 9) | 0x3f800000u) - 1.0f;
  float u = __fadd_rn(__fmul_rn(f, 1.99999994f), -0.99999994f);
  u = fmaxf(-0.99999994f, u);
  float w = -log1pf(-u*u);
  float p;
  if (w < 5.0f){
    w -= 2.5f;
    p = 2.81022636e-08f;
    p = fmaf(p, w, 3.43273939e-07f);
    p = fmaf(p, w, -3.5233877e-06f);
    p = fmaf(p, w, -4.39150654e-06f);
    p = fmaf(p, w, 0.00021858087f);
    p = fmaf(p, w, -0.00125372503f);
    p = fmaf(p, w, -0.00417768164f);
    p = fmaf(p, w, 0.246640727f);
    p = fmaf(p, w, 1.50140941f);
  } else {
    w = sqrtf(w) - 3.0f;
    p = -0.000200214257f;
    p = fmaf(p, w, 0.000100950558f);
    p = fmaf(p, w, 0.00134934322f);
    p = fmaf(p, w, -0.00367342844f);
    p = fmaf(p, w, 0.00573950773f);
    p = fmaf(p, w, -0.0076224613f);
    p = fmaf(p, w, 0.00943887047f);
    p = fmaf(p, w, 1.00167406f);
    p = fmaf(p, w, 2.83297682f);
  }
  eps[j] = 1.41421356237f * (p * u);
}

// ---------------- total_input_fea output (coalesced, 2048 elems/block) ------
__global__ void tif_v2(const float* __restrict__ atom, const float* __restrict__ nbr,
                       const int* __restrict__ idx, float* __restrict__ out){
  int e0 = blockIdx.x*2048 + threadIdx.x;
#pragma unroll
  for (int i=0;i<8;++i){
    int e = e0 + i*256;
    int r = e/225, c = e - r*225;
    float v;
    if (c < 92)       v = atom[(r/12)*92 + c];
    else if (c < 184) v = atom[idx[r]*92 + (c-92)];
    else              v = nbr[(size_t)r*41 + (c-184)];
    out[(size_t)e] = v;
  }
}

// ---------------- embeddings (write bf16 masters) ----------------
__global__ void embed_atom_kernel(const float* __restrict__ atom, const float* __restrict__ W,
                                  const float* __restrict__ bias, ushort_t* __restrict__ a0){
  __shared__ float row[92];
  int i = blockIdx.x; int t = threadIdx.x; // 128
  if (t < 92) row[t] = atom[i*92+t];
  __syncthreads();
  float s = bias[t];
#pragma unroll
  for (int k=0;k<92;++k) s = fmaf(row[k], W[k*128+t], s);
  a0[(size_t)i*128+t] = f2bf(s);
}

__global__ void embed_bond_kernel(const float* __restrict__ nbr, const float* __restrict__ W,
                                  const float* __restrict__ bias, ushort_t* __restrict__ nb0){
  __shared__ float rows[4][41];
  int r0 = blockIdx.x*4; int t = threadIdx.x; // 256
  if (t < 164) rows[t/41][t%41] = nbr[(size_t)r0*41 + t];
  __syncthreads();
  int rr = t >> 6, c = t & 63;
  float s = bias[c];
#pragma unroll
  for (int k=0;k<41;++k) s = fmaf(rows[rr][k], W[k*64+c], s);
  nb0[(size_t)(r0+rr)*64 + c] = f2bf(s);
}

// ---------------- idx histogram ----------------
__global__ void cnt_kernel(const int* __restrict__ idx, int* __restrict__ cnt){
  int e = blockIdx.x*256 + threadIdx.x;
  if (e < NM) atomicAdd(&cnt[idx[e]], 1);
}

// ---------------- weight transpose + bf16: Wt[o][k] = bf16(W[k][o]) ----------------
__global__ void wtr_kernel(const float* __restrict__ W, int NO, ushort_t* __restrict__ Wt){
  __shared__ ushort_t tile[32][33];
  int k0 = blockIdx.x*32, o0 = blockIdx.y*32;
  int tx = threadIdx.x & 31, ty = threadIdx.x >> 5; // 256 thr
#pragma unroll
  for (int i = ty; i < 32; i += 8)
    tile[i][tx] = f2bf(W[(size_t)(k0+i)*NO + o0 + tx]);
  __syncthreads();
#pragma unroll
  for (int i = ty; i < 32; i += 8)
    Wt[(size_t)(o0+i)*320 + k0 + tx] = tile[tx][i];
}

// ---------------- column sums for exact mean (over bf16 masters) ----------------
__global__ void colsum_a_kernel(const ushort_t* __restrict__ a, const int* __restrict__ cnt,
                                double* __restrict__ cs){
  int c = threadIdx.x; // 128
  float p1 = 0.f, p2 = 0.f;
  int i0 = blockIdx.x*128;
  for (int i=i0; i<i0+128; ++i){
    float v = bf2f(a[(size_t)i*128+c]);
    p1 += v;
    p2 += (float)cnt[i] * v;
  }
  atomicAdd(&cs[c], (double)p1);
  atomicAdd(&cs[128+c], (double)p2);
}

__global__ void colsum_nb_kernel(const ushort_t* __restrict__ nb, double* __restrict__ cs){
  __shared__ float sh[4][64];
  int t = threadIdx.x; // 256
  int c = t & 63, pr = t >> 6;
  float p = 0.f;
  size_t r0 = (size_t)blockIdx.x * 512;
  for (size_t r = r0 + pr; r < r0 + 512; r += 4) p += bf2f(nb[r*64 + c]);
  sh[pr][c] = p;
  __syncthreads();
  if (pr == 0){
    float s = sh[0][c]+sh[1][c]+sh[2][c]+sh[3][c];
    atomicAdd(&cs[256+c], (double)s);
  }
}

__global__ void mean_kernel(const double* __restrict__ cs, const ushort_t* __restrict__ Wt,
                            int NO, float* __restrict__ mean){
  int o = blockIdx.x*64 + threadIdx.x;
  if (o >= NO) return;
  const ushort_t* wr = Wt + (size_t)o*320;
  double s = 0.0;
  for (int k=0;k<128;++k)   s += 12.0*cs[k]*(double)bf2f(wr[k]);
  for (int k=128;k<320;++k) s += cs[k]*(double)bf2f(wr[k]);
  mean[o] = (float)(s / (double)NM);
}

// ---------------- fused MFMA conv GEMM (ga+gb in one, NO=384) ----------------
// O[r,o] = sum_k total[r,k]*Wt[o,k] - mean[o]; total[r] = [a[r/12] | a[idx[r]] | nb[r]]
// Tile 128 rows x 128 cols, 4 waves (each 32 rows x 128 cols). A and B double-buffered.
__launch_bounds__(256, 3)
__global__ void conv_gemm_v2(const ushort_t* __restrict__ a_bf, const ushort_t* __restrict__ nb_bf,
                             const int* __restrict__ idx, const ushort_t* __restrict__ Wt,
                             const float* __restrict__ mean, __half* __restrict__ O,
                             float* __restrict__ ssq){
  __shared__ ushort_t As[2][128*40];  // row stride 40 elems (80B): uniform bank tiling
  __shared__ ushort_t Bs[2][128*40];
  __shared__ int      idxs[128];
  __shared__ float    sqred[128];
  const int t = threadIdx.x;
  const int lane = t & 63, w = t >> 6;
  const int row0 = blockIdx.x * 128;
  const int col0 = blockIdx.y * 128;
  if (t < 128){ idxs[t] = idx[row0 + t]; sqred[t] = 0.f; }

  uint4 pa[2], pb[2];
  auto load_step = [&](int ks){
#pragma unroll
    for (int i=0;i<2;++i){
      int e = t + i*256;            // 0..511
      int r = e >> 2, ch = e & 3;
      const ushort_t* p;
      if (ks < 4)      p = a_bf + (size_t)((row0+r)/12)*128 + ks*32 + ch*8;
      else if (ks < 8) p = a_bf + (size_t)idxs[r]*128 + (ks-4)*32 + ch*8;
      else             p = nb_bf + (size_t)(row0+r)*64 + (ks-8)*32 + ch*8;
      pa[i] = *(const uint4*)p;
      pb[i] = *(const uint4*)(Wt + (size_t)(col0+r)*320 + ks*32 + ch*8);
    }
  };
  auto write_step = [&](int b_){
#pragma unroll
    for (int i=0;i<2;++i){
      int e = t + i*256;
      int r = e >> 2, ch = e & 3;
      *(uint4*)&As[b_][r*40 + ch*8] = pa[i];
      *(uint4*)&Bs[b_][r*40 + ch*8] = pb[i];
    }
  };

  load_step(0); write_step(0);   // ks=0 path doesn't use idxs
  __syncthreads();

  f32x4 acc[2][8] = {};
#define ACCS_ "+v"(acc[0][0]),"+v"(acc[0][1]),"+v"(acc[0][2]),"+v"(acc[0][3]), \
              "+v"(acc[0][4]),"+v"(acc[0][5]),"+v"(acc[0][6]),"+v"(acc[0][7]), \
              "+v"(acc[1][0]),"+v"(acc[1][1]),"+v"(acc[1][2]),"+v"(acc[1][3]), \
              "+v"(acc[1][4]),"+v"(acc[1][5]),"+v"(acc[1][6]),"+v"(acc[1][7])
  asm volatile("s_nop 3" : ACCS_);   // VALU zero-init -> MFMA SrcC hazard guard

  const int lm = lane & 15, lg = lane >> 4;
  int buf = 0;
#pragma unroll
  for (int ks = 0; ks < 10; ++ks){
    if (ks < 9) load_step(ks+1);
    i32x4 afr[2], bfr[8];
#pragma unroll
    for (int fm = 0; fm < 2; ++fm)
      afr[fm] = *(const i32x4*)&As[buf][(w*32 + fm*16 + lm)*40 + lg*8];
#pragma unroll
    for (int fn = 0; fn < 8; ++fn)
      bfr[fn] = *(const i32x4*)&Bs[buf][(fn*16 + lm)*40 + lg*8];
#pragma unroll
    for (int fm = 0; fm < 2; ++fm)
#pragma unroll
      for (int fn = 0; fn < 8; ++fn)
        mfma_bf16_16x16x32(acc[fm][fn], afr[fm], bfr[fn]);
    if (ks < 9) write_step(buf^1);
    __syncthreads();
    buf ^= 1;
  }

  asm volatile("s_nop 7\n\ts_nop 7" : ACCS_);  // MFMA -> VALU read hazard guard
#undef ACCS_

  // epilogue: subtract exact mean, store f16 (stride 384), reduce ssq
  float m8[8];
#pragma unroll
  for (int fn=0; fn<8; ++fn) m8[fn] = mean[col0 + fn*16 + lm];
  float sq[8] = {0.f,0.f,0.f,0.f,0.f,0.f,0.f,0.f};
#pragma unroll
  for (int fm=0; fm<2; ++fm){
#pragma unroll
    for (int fn=0; fn<8; ++fn){
#pragma unroll
      for (int j=0; j<4; ++j){
        float xc = acc[fm][fn][j] - m8[fn];
        int r = row0 + w*32 + fm*16 + lg*4 + j;
        O[(size_t)r*384 + col0 + fn*16 + lm] = __float2half(xc);
        sq[fn] += xc*xc;
      }
    }
  }
#pragma unroll
  for (int fn=0; fn<8; ++fn) atomicAdd(&sqred[fn*16 + lm], sq[fn]);
  __syncthreads();
  if (t < 128) atomicAdd(&ssq[col0 + t], sqred[t]);
}

__global__ void finalize_rs(const float* __restrict__ ssq, int C, float* __restrict__ rs){
  int c = blockIdx.x*256 + threadIdx.x;
  if (c < C) rs[c] = rsqrtf(ssq[c]/(float)NM + 1e-5f);
}

// ---------------- conv apply kernels (values mean-centered: BN = x*rs*g + b) ----
__global__ void apply_ga(const __half* __restrict__ ga, const float* __restrict__ rs,
                         const float* __restrict__ g1a, const float* __restrict__ b1a,
                         float* __restrict__ asum){
  int i = blockIdx.x; int c = threadIdx.x; // 128
  float gf  = g1a[c]     * rs[c];      float bf_ = b1a[c];
  float gc  = g1a[c+128] * rs[c+128];  float bc_ = b1a[c+128];
  float s = 0.f;
  size_t base = (size_t)i*12*384;
#pragma unroll
  for (int j=0;j<12;++j){
    float vf = __half2float(ga[base + j*384 + c]);
    float vc = __half2float(ga[base + j*384 + c + 128]);
    s += sigmoidf_(fmaf(vf, gf, bf_)) * softplusf_(fmaf(vc, gc, bc_));
  }
  asum[(size_t)i*128+c] = s;
}

__global__ void asum_stats(const float* __restrict__ asum, double* __restrict__ st){
  int c = threadIdx.x; // 128
  float s1 = 0.f, s2 = 0.f;
  int i0 = blockIdx.x*128;
  for (int i=i0;i<i0+128;++i){
    float v = asum[(size_t)i*128+c];
    s1 += v; s2 += v*v;
  }
  atomicAdd(&st[c], (double)s1);
  atomicAdd(&st[128+c], (double)s2);
}

__global__ void finalize_mr2(const double* __restrict__ st, float* __restrict__ mr2){
  int c = threadIdx.x; // 128
  double mean = st[c] / (double)N_ATOM;
  double var  = st[128+c] / (double)N_ATOM - mean*mean;
  mr2[c]     = (float)mean;
  mr2[128+c] = rsqrtf((float)var + 1e-5f);
}

__global__ void apply_out1(ushort_t* __restrict__ a0, const float* __restrict__ asum,
                           const float* __restrict__ mr2, const float* __restrict__ g2a,
                           const float* __restrict__ b2a){
  int e = blockIdx.x*256 + threadIdx.x; // n*128
  int c = e & 127;
  float g = g2a[c]*mr2[128+c];
  float b = b2a[c] - mr2[c]*g;
  a0[e] = f2bf(softplusf_(bf2f(a0[e]) + fmaf(asum[e], g, b)));
}

__global__ void apply_gb(const __half* __restrict__ gb, ushort_t* __restrict__ nb,
                         const float* __restrict__ rs, const float* __restrict__ g1b,
                         const float* __restrict__ b1b){
  int e = blockIdx.x*256 + threadIdx.x; // NM*64
  int row = e >> 6, c = e & 63;
  float vf = __half2float(gb[(size_t)row*384 + 256 + c]);
  float vc = __half2float(gb[(size_t)row*384 + 256 + c + 64]);
  float gf  = g1b[c]    * rs[256+c];     float bf_ = b1b[c];
  float gc  = g1b[c+64] * rs[256+c+64];  float bc_ = b1b[c+64];
  nb[e] = f2bf(softplusf_(bf2f(nb[e]) + sigmoidf_(fmaf(vf,gf,bf_)) * softplusf_(fmaf(vc,gc,bc_))));
}

// ---------------- pooling / VAE / decode ----------------
__global__ void pool_a_kernel(const ushort_t* __restrict__ a, float* __restrict__ pooled){
  int b = blockIdx.x; int c = threadIdx.x; // 128
  float s = 0.f;
  for (int i=0;i<128;++i) s += bf2f(a[(size_t)((b<<7)+i)*128 + c]);
  pooled[b*896 + c] = softplusf_(s * (1.f/128.f));
}

__launch_bounds__(768)
__global__ void pool_n_kernel(const ushort_t* __restrict__ nb, float* __restrict__ pooled){
  int b = blockIdx.x; int t = threadIdx.x; // 768
  float s = 0.f;
  for (int i=0;i<128;++i) s += bf2f(nb[(size_t)((b<<7)+i)*768 + t]);
  pooled[b*896 + 128 + t] = softplusf_(s * (1.f/128.f));
}

__global__ void muz_kernel(const float* __restrict__ pooled, const float* __restrict__ muW,
                           const float* __restrict__ mub, const float* __restrict__ lvW,
                           const float* __restrict__ lvb, const float* __restrict__ eps,
                           float* __restrict__ out_mu, float* __restrict__ out_lv,
                           float* __restrict__ out_z, float* __restrict__ zws){
  int t = threadIdx.x; // 256 -> (b,l)
  int b = t >> 1, l = t & 1;
  const float* pr = pooled + b*896;
  float smu = mub[l], slv = lvb[l];
  for (int k=0;k<896;++k){
    float p = pr[k];
    smu = fmaf(p, muW[k*2+l], smu);
    slv = fmaf(p, lvW[k*2+l], slv);
  }
  out_mu[t] = smu; out_lv[t] = slv;
  float zv = fmaf(eps[t], __expf(0.5f*slv), smu);
  out_z[t] = zv; zws[t] = zv;
}

__global__ void compute_f_kernel(const float* __restrict__ zws, const float* __restrict__ decW,
                                 const float* __restrict__ decb, const float* __restrict__ pooled,
                                 float* __restrict__ f){
  int b = blockIdx.x;
  float z0 = zws[b*2], z1 = zws[b*2+1];
  for (int k = threadIdx.x; k < 896; k += 256){
    float zd = fmaf(z0, decW[k], fmaf(z1, decW[896+k], decb[k]));
    f[b*896+k] = zd / pooled[b*896+k];
  }
}

__global__ void dec_atom_kernel(ushort_t* __restrict__ a, const float* __restrict__ f){
  int e = blockIdx.x*256+threadIdx.x; // n*128
  int c = e & 127; int b = e >> 14;
  a[e] = f2bf(softplusf_(bf2f(a[e]) * f[b*896 + c]));
}

__global__ void dec_bond_kernel(ushort_t* __restrict__ nb, const float* __restrict__ f){
  int i = blockIdx.x; int off = blockIdx.y*256 + threadIdx.x; // off < 768
  int b = i >> 7;
  size_t e = (size_t)i*768 + off;
  nb[e] = f2bf(softplusf_(bf2f(nb[e]) * f[b*896 + 128 + off]));
}

// ---------------- final embeddings ----------------
__global__ void embed_atom2_kernel(const ushort_t* __restrict__ a, const float* __restrict__ W,
                                   const float* __restrict__ bias, float* __restrict__ za2){
  __shared__ float row[128];
  int i = blockIdx.x; int t = threadIdx.x; // 128
  row[t] = bf2f(a[(size_t)i*128+t]);
  __syncthreads();
  if (t < 92){
    float s = bias[t];
#pragma unroll
    for (int k=0;k<128;++k) s = fmaf(row[k], W[k*92+t], s);
    za2[(size_t)i*92+t] = sigmoidf_(s);
  }
}

// bproj[r,o] = sigmoid(sum_k nb[r,k]*W[k,o] + b[o]), 6 rows/block
__global__ void bproj_kernel(const ushort_t* __restrict__ nb, const float* __restrict__ W,
                             const float* __restrict__ bias, float* __restrict__ bp){
  __shared__ float Ws[64][41];
  __shared__ float rows[6][64];
  int t = threadIdx.x; // 256
  for (int e=t; e<64*41; e+=256) Ws[e/41][e%41] = W[e];
  int r0 = blockIdx.x*6;
  for (int e=t; e<6*64; e+=256){
    int rr = e>>6, c = e&63;
    rows[rr][c] = bf2f(nb[(size_t)(r0+rr)*64 + c]);
  }
  __syncthreads();
  if (t < 246){
    int rr = t/41, o = t - rr*41;
    float s = bias[o];
#pragma unroll
    for (int k=0;k<64;++k) s = fmaf(rows[rr][k], Ws[k][o], s);
    bp[(size_t)(r0+rr)*41 + o] = sigmoidf_(s);
  }
}

__global__ void zdec_v2(const float* __restrict__ za2, const float* __restrict__ bp,
                        const int* __restrict__ idx, float* __restrict__ out){
  int e0 = blockIdx.x*2048 + threadIdx.x;
#pragma unroll
  for (int i=0;i<8;++i){
    int e = e0 + i*256;
    int r = e/225, c = e - r*225;
    float v;
    if (c < 92)       v = za2[(size_t)(r/12)*92 + c];
    else if (c < 184) v = za2[(size_t)idx[r]*92 + (c-92)];
    else              v = bp[(size_t)r*41 + (c-184)];
    out[(size_t)e] = v;
  }
}

// ---------------- host side ----------------
struct WsPlan {
  ushort_t *Abf, *NBbf, *Wt;
  __half* big;
  float *asum, *pooled, *fbuf, *zws, *eps, *mean, *rs, *mr2, *ssq;
  int* cnt;
  double *cs, *st;
};

static void conv_pass(const WsPlan& P, const int* idx,
                      const float* Wa, const float* Wb,
                      const float* g1a, const float* b1a, const float* g1b, const float* b1b,
                      const float* g2a, const float* b2a,
                      hipStream_t stream){
  wtr_kernel<<<dim3(10,8), 256, 0, stream>>>(Wa, 256, P.Wt);
  wtr_kernel<<<dim3(10,4), 256, 0, stream>>>(Wb, 128, P.Wt + 256*320);
  // zero cs(320 f64) + st(256 f64) + ssq(384 f32) in one contiguous memset
  hipMemsetAsync(P.cs, 0, 320*8 + 256*8 + 384*4, stream);
  colsum_a_kernel<<<128, 128, 0, stream>>>(P.Abf, P.cnt, P.cs);
  colsum_nb_kernel<<<NM/512, 256, 0, stream>>>(P.NBbf, P.cs);
  mean_kernel<<<6, 64, 0, stream>>>(P.cs, P.Wt, 384, P.mean);
  // fused ga+gb GEMM + ssq
  conv_gemm_v2<<<dim3(NM/128, 3), 256, 0, stream>>>(P.Abf, P.NBbf, idx, P.Wt, P.mean, P.big, P.ssq);
  finalize_rs<<<2, 256, 0, stream>>>(P.ssq, 384, P.rs);
  apply_ga<<<N_ATOM, 128, 0, stream>>>(P.big, P.rs, g1a, b1a, P.asum);
  asum_stats<<<128, 128, 0, stream>>>(P.asum, P.st);
  finalize_mr2<<<1, 128, 0, stream>>>(P.st, P.mr2);
  apply_out1<<<N_ATOM*128/256, 256, 0, stream>>>(P.Abf, P.asum, P.mr2, g2a, b2a);
  apply_gb<<<NM*64/256, 256, 0, stream>>>(P.big, P.NBbf, P.rs, g1b, b1b);
}

extern "C" void kernel_launch(void* const* d_in, const int* in_sizes, int n_in,
                              void* d_out, int out_size, void* d_ws, size_t ws_size,
                              hipStream_t stream) {
  (void)in_sizes; (void)n_in; (void)out_size; (void)ws_size;
  const float* atom_fea   = (const float*)d_in[0];
  const float* nbr_fea    = (const float*)d_in[1];
  const int*   idx        = (const int*)d_in[2];
  const float* emb_atom_W = (const float*)d_in[4];
  const float* emb_atom_b = (const float*)d_in[5];
  const float* emb_bond_W = (const float*)d_in[6];
  const float* emb_bond_b = (const float*)d_in[7];
  const float* emb_atom2_W= (const float*)d_in[8];
  const float* emb_atom2_b= (const float*)d_in[9];
  const float* emb_bond2_W= (const float*)d_in[10];
  const float* emb_bond2_b= (const float*)d_in[11];
  const float* mu_W       = (const float*)d_in[12];
  const float* mu_b       = (const float*)d_in[13];
  const float* lv_W       = (const float*)d_in[14];
  const float* lv_b       = (const float*)d_in[15];
  const float* dec_W      = (const float*)d_in[16];
  const float* dec_b      = (const float*)d_in[17];
  const float* c1_Wa  = (const float*)d_in[18];
  const float* c1_Wb  = (const float*)d_in[19];
  const float* c1_g1a = (const float*)d_in[20];
  const float* c1_b1a = (const float*)d_in[21];
  const float* c1_g1b = (const float*)d_in[22];
  const float* c1_b1b = (const float*)d_in[23];
  const float* c1_g2a = (const float*)d_in[24];
  const float* c1_b2a = (const float*)d_in[25];
  const float* c2_Wa  = (const float*)d_in[26];
  const float* c2_Wb  = (const float*)d_in[27];
  const float* c2_g1a = (const float*)d_in[28];
  const float* c2_b1a = (const float*)d_in[29];
  const float* c2_g1b = (const float*)d_in[30];
  const float* c2_b1b = (const float*)d_in[31];
  const float* c2_g2a = (const float*)d_in[32];
  const float* c2_b2a = (const float*)d_in[33];

  float* out = (float*)d_out;

  // ---------------- workspace layout ----------------
  WsPlan P;
  char* w = (char*)d_ws;
  auto alloc = [&](size_t bytes) -> char* {
    char* p = w; w += (bytes + 255) & ~(size_t)255; return p;
  };
  P.Abf    = (ushort_t*)alloc((size_t)N_ATOM*128*2);     // 4 MB
  P.NBbf   = (ushort_t*)alloc((size_t)NM*64*2);          // 24 MB
  P.big    = (__half*)  alloc((size_t)NM*384*2);         // 144 MB
  P.asum   = (float*)   alloc((size_t)N_ATOM*128*4);     // 8 MB (also za2)
  P.pooled = (float*)   alloc(114688*4);
  P.fbuf   = (float*)   alloc(114688*4);
  P.Wt     = (ushort_t*)alloc(384*320*2);
  P.zws    = (float*)   alloc(256*4);
  P.eps    = (float*)   alloc(256*4);
  P.mean   = (float*)   alloc(384*4);
  P.rs     = (float*)   alloc(384*4);
  P.mr2    = (float*)   alloc(256*4);
  P.cnt    = (int*)     alloc(N_ATOM*4);
  P.cs     = (double*)  alloc(320*8);   // cs, st, ssq contiguous (one memset)
  P.st     = (double*)  alloc(256*8);
  P.ssq    = (float*)   alloc(384*4);
  float* za2   = P.asum;                 // reuse after conv stacks
  float* bproj = (float*)P.big;          // reuse big in the final phase

  gen_eps_kernel<<<1, 256, 0, stream>>>(P.eps);
  tif_v2<<<21600, 256, 0, stream>>>(atom_fea, nbr_fea, idx, out + O_TIF);
  embed_atom_kernel<<<N_ATOM, 128, 0, stream>>>(atom_fea, emb_atom_W, emb_atom_b, P.Abf);
  embed_bond_kernel<<<NM/4, 256, 0, stream>>>(nbr_fea, emb_bond_W, emb_bond_b, P.NBbf);
  hipMemsetAsync(P.cnt, 0, N_ATOM*sizeof(int), stream);
  cnt_kernel<<<NM/256, 256, 0, stream>>>(idx, P.cnt);

  for (int L=0; L<3; ++L){
    conv_pass(P, idx, c1_Wa + (size_t)L*320*256, c1_Wb + (size_t)L*320*128,
              c1_g1a+L*256, c1_b1a+L*256, c1_g1b+L*128, c1_b1b+L*128,
              c1_g2a+L*128, c1_b2a+L*128, stream);
  }

  pool_a_kernel<<<NCRY, 128, 0, stream>>>(P.Abf, P.pooled);
  pool_n_kernel<<<NCRY, 768, 0, stream>>>(P.NBbf, P.pooled);
  muz_kernel<<<1, 256, 0, stream>>>(P.pooled, mu_W, mu_b, lv_W, lv_b, P.eps,
                                    out + O_MU, out + O_LV, out + O_Z, P.zws);
  compute_f_kernel<<<NCRY, 256, 0, stream>>>(P.zws, dec_W, dec_b, P.pooled, P.fbuf);
  dec_atom_kernel<<<N_ATOM*128/256, 256, 0, stream>>>(P.Abf, P.fbuf);
  dim3 gdb(N_ATOM, 3);
  dec_bond_kernel<<<gdb, 256, 0, stream>>>(P.NBbf, P.fbuf);

  for (int L=0; L<3; ++L){
    conv_pass(P, idx, c2_Wa + (size_t)L*320*256, c2_Wb + (size_t)L*320*128,
              c2_g1a+L*256, c2_b1a+L*256, c2_g1b+L*128, c2_b1b+L*128,
              c2_g2a+L*128, c2_b2a+L*128, stream);
  }

  embed_atom2_kernel<<<N_ATOM, 128, 0, stream>>>(P.Abf, emb_atom2_W, emb_atom2_b, za2);
  bproj_kernel<<<NM/6, 256, 0, stream>>>(P.NBbf, emb_bond2_W, emb_bond2_b, bproj);
  zdec_v2<<<21600, 256, 0, stream>>>(za2, bproj, idx, out + O_ZDEC);
}